// Round 7
// baseline (186.213 us; speedup 1.0000x reference)
//
#include <hip/hip_runtime.h>
#include <math.h>

#define T_LEN 256
#define HID 10

typedef float v2f __attribute__((ext_vector_type(2)));

// ds_swizzle compile-time pattern (BitMode): src = ((lane & and) | or) ^ xor
// broadcast lane J within each 16-lane group: PAT = (J<<5) | 0x10
// xor-butterfly by M:                          PAT = (M<<10) | 0x1f
template <int PAT>
__device__ __forceinline__ float swz(float v) {
    return __int_as_float(__builtin_amdgcn_ds_swizzle(__float_as_int(v), PAT));
}

// v_pk_fma_f32 with op_sel scalar-broadcast: both halves of the op read the
// LO (or HI) 32-bit word of src0 -> a scalar h_j multiplies a packed weight
// pair with ZERO splat movs.
#define FMA_SEED(ACC, HP, W, B)                                              \
    asm("v_pk_fma_f32 %0, %1, %2, %3 op_sel_hi:[0,1,1]"                      \
        : "=v"(ACC) : "v"(HP), "v"(W), "v"(B));
#define FMA_LO(ACC, HP, W)                                                   \
    asm("v_pk_fma_f32 %0, %1, %2, %0 op_sel_hi:[0,1,1]"                      \
        : "+v"(ACC) : "v"(HP), "v"(W));
#define FMA_HI(ACC, HP, W)                                                   \
    asm("v_pk_fma_f32 %0, %1, %2, %0 op_sel:[1,0,0]"                         \
        : "+v"(ACC) : "v"(HP), "v"(W));

// setup-only accurate softplus
__device__ __forceinline__ float softplus_f(float x) {
    return fmaxf(x, 0.0f) + log1pf(expf(-fabsf(x)));
}
__device__ __forceinline__ float samp(const float* mu, const float* rho,
                                      const float* eps, int i) {
    return mu[i] + softplus_f(rho[i]) * eps[i];
}

// sigmoid = rcp(1 + 2^(-log2e*x)) : mul, exp, add, rcp
__device__ __forceinline__ float fast_sigmoid(float x) {
    float e = __builtin_amdgcn_exp2f(-1.442695040888963f * x);
    return __builtin_amdgcn_rcpf(1.0f + e);
}
// tanh = 1 - 2*rcp(2^(2*log2e*x) + 1)
__device__ __forceinline__ float fast_tanh(float x) {
    float e = __builtin_amdgcn_exp2f(2.885390081777927f * x);
    return fmaf(-2.0f, __builtin_amdgcn_rcpf(e + 1.0f), 1.0f);
}

// One timestep. All 11 broadcasts (x_t + h_0..h_9) issued up front as
// independent ds_swizzles (latencies overlap; compiler emits fine-grained
// lgkmcnt). Dot = 22 op_sel pk_fmas, no glue. TLP=2 waves/SIMD hides the
// dependent-chain and swizzle latency (the only mechanism that worked, R1).
#define TSTEP(TI)                                                            \
    {                                                                        \
        v2f hp0, hp1, hp2, hp3, hp4, hp5;                                    \
        hp0.x = swz<((TI) << 5) | 0x10>(xcur);                               \
        hp0.y = swz<(0 << 5) | 0x10>(hk);                                    \
        hp1.x = swz<(1 << 5) | 0x10>(hk);                                    \
        hp1.y = swz<(2 << 5) | 0x10>(hk);                                    \
        hp2.x = swz<(3 << 5) | 0x10>(hk);                                    \
        hp2.y = swz<(4 << 5) | 0x10>(hk);                                    \
        hp3.x = swz<(5 << 5) | 0x10>(hk);                                    \
        hp3.y = swz<(6 << 5) | 0x10>(hk);                                    \
        hp4.x = swz<(7 << 5) | 0x10>(hk);                                    \
        hp4.y = swz<(8 << 5) | 0x10>(hk);                                    \
        hp5.x = swz<(9 << 5) | 0x10>(hk);                                    \
        hp5.y = 0.0f;                                                        \
        v2f a01, a23;                                                        \
        FMA_SEED(a01, hp0, wx01, bb01)   /* x*wih + b      */                \
        FMA_SEED(a23, hp0, wx23, bb23)                                       \
        FMA_HI(a01, hp0, wh01[0]) FMA_HI(a23, hp0, wh23[0])  /* h0 */        \
        FMA_LO(a01, hp1, wh01[1]) FMA_LO(a23, hp1, wh23[1])  /* h1 */        \
        FMA_HI(a01, hp1, wh01[2]) FMA_HI(a23, hp1, wh23[2])  /* h2 */        \
        FMA_LO(a01, hp2, wh01[3]) FMA_LO(a23, hp2, wh23[3])  /* h3 */        \
        FMA_HI(a01, hp2, wh01[4]) FMA_HI(a23, hp2, wh23[4])  /* h4 */        \
        FMA_LO(a01, hp3, wh01[5]) FMA_LO(a23, hp3, wh23[5])  /* h5 */        \
        FMA_HI(a01, hp3, wh01[6]) FMA_HI(a23, hp3, wh23[6])  /* h6 */        \
        FMA_LO(a01, hp4, wh01[7]) FMA_LO(a23, hp4, wh23[7])  /* h7 */        \
        FMA_HI(a01, hp4, wh01[8]) FMA_HI(a23, hp4, wh23[8])  /* h8 */        \
        FMA_LO(a01, hp5, wh01[9]) FMA_LO(a23, hp5, wh23[9])  /* h9 */        \
        float si = fast_sigmoid(a01.x);                                      \
        float sf = fast_sigmoid(a01.y);                                      \
        float tg = fast_tanh(a23.x);                                         \
        float so = fast_sigmoid(a23.y);                                      \
        c = fmaf(sf, c, si * tg);                                            \
        hk = so * fast_tanh(c);                                              \
    }

__global__ __launch_bounds__(256, 2) void bayes_lstm_kernel(
    const float* __restrict__ x,
    const float* __restrict__ w_ih_mu, const float* __restrict__ w_ih_rho,
    const float* __restrict__ w_hh_mu, const float* __restrict__ w_hh_rho,
    const float* __restrict__ b_mu,    const float* __restrict__ b_rho,
    const float* __restrict__ eps_ih,  const float* __restrict__ eps_hh,
    const float* __restrict__ eps_b,
    const float* __restrict__ lin_w,   const float* __restrict__ lin_b,
    float* __restrict__ out)
{
    const int tid  = threadIdx.x;
    const int k    = tid & 15;           // hidden unit (active: k < 10)
    const int slot = tid >> 4;           // 0..15
    const int b    = blockIdx.x * 16 + slot;   // one element per slot (TLP=2)

    // ---- sample weights as {i,f} / {g,o} column pairs (zero for k>=10) ----
    v2f wh01[HID], wh23[HID];
    v2f wx01, wx23, bb01, bb23;
    wx01.x = wx01.y = 0.f; wx23.x = wx23.y = 0.f;
    bb01.x = bb01.y = 0.f; bb23.x = bb23.y = 0.f;
    float lw = 0.f;
#pragma unroll
    for (int j = 0; j < HID; ++j) {
        wh01[j].x = wh01[j].y = 0.f;
        wh23[j].x = wh23[j].y = 0.f;
    }
    if (k < HID) {
        const int c0 = k, c1 = HID + k, c2 = 2 * HID + k, c3 = 3 * HID + k;
        wx01.x = samp(w_ih_mu, w_ih_rho, eps_ih, c0);
        wx01.y = samp(w_ih_mu, w_ih_rho, eps_ih, c1);
        wx23.x = samp(w_ih_mu, w_ih_rho, eps_ih, c2);
        wx23.y = samp(w_ih_mu, w_ih_rho, eps_ih, c3);
        bb01.x = samp(b_mu, b_rho, eps_b, c0);
        bb01.y = samp(b_mu, b_rho, eps_b, c1);
        bb23.x = samp(b_mu, b_rho, eps_b, c2);
        bb23.y = samp(b_mu, b_rho, eps_b, c3);
#pragma unroll
        for (int j = 0; j < HID; ++j) {
            wh01[j].x = samp(w_hh_mu, w_hh_rho, eps_hh, j * 4 * HID + c0);
            wh01[j].y = samp(w_hh_mu, w_hh_rho, eps_hh, j * 4 * HID + c1);
            wh23[j].x = samp(w_hh_mu, w_hh_rho, eps_hh, j * 4 * HID + c2);
            wh23[j].y = samp(w_hh_mu, w_hh_rho, eps_hh, j * 4 * HID + c3);
        }
        lw = lin_w[k];
    }

    // ---- recurrence: lane k holds h_k; broadcasts via immediate swizzle ----
    float hk = 0.f, c = 0.f;

    const float* xrow = x + (size_t)b * T_LEN;
    float xcur = xrow[k];                // chunk 0: lane k holds x[t=k]

    for (int to = 0; to < 16; ++to) {
        float xnext = 0.f;
        if (to < 15) xnext = xrow[(to + 1) * 16 + k];   // prefetch next chunk
        TSTEP(0)  TSTEP(1)  TSTEP(2)  TSTEP(3)
        TSTEP(4)  TSTEP(5)  TSTEP(6)  TSTEP(7)
        TSTEP(8)  TSTEP(9)  TSTEP(10) TSTEP(11)
        TSTEP(12) TSTEP(13) TSTEP(14) TSTEP(15)
        xcur = xnext;
    }

    // ---- linear head: lane k holds final h[k]; xor-swizzle reduce ----
    float pa = hk * lw;                  // lanes >= 10 contribute 0
    pa += swz<(1 << 10) | 0x1f>(pa);
    pa += swz<(2 << 10) | 0x1f>(pa);
    pa += swz<(4 << 10) | 0x1f>(pa);
    pa += swz<(8 << 10) | 0x1f>(pa);
    if (k == 0) out[b] = pa + lin_b[0];
}

extern "C" void kernel_launch(void* const* d_in, const int* in_sizes, int n_in,
                              void* d_out, int out_size, void* d_ws, size_t ws_size,
                              hipStream_t stream) {
    const float* x        = (const float*)d_in[0];
    const float* w_ih_mu  = (const float*)d_in[1];
    const float* w_ih_rho = (const float*)d_in[2];
    const float* w_hh_mu  = (const float*)d_in[3];
    const float* w_hh_rho = (const float*)d_in[4];
    const float* b_mu     = (const float*)d_in[5];
    const float* b_rho    = (const float*)d_in[6];
    const float* eps_ih   = (const float*)d_in[7];
    const float* eps_hh   = (const float*)d_in[8];
    const float* eps_b    = (const float*)d_in[9];
    const float* lin_w    = (const float*)d_in[10];
    const float* lin_b    = (const float*)d_in[11];
    float* out = (float*)d_out;

    const int n_b = in_sizes[0] / T_LEN;     // 8192
    dim3 grid(n_b / 16), block(256);         // 1 element per 16-lane slot, TLP=2
    hipLaunchKernelGGL(bayes_lstm_kernel, grid, block, 0, stream,
                       x, w_ih_mu, w_ih_rho, w_hh_mu, w_hh_rho, b_mu, b_rho,
                       eps_ih, eps_hh, eps_b, lin_w, lin_b, out);
}